// Round 1
// baseline (287.902 us; speedup 1.0000x reference)
//
#include <hip/hip_runtime.h>
#include <hip/hip_bf16.h>
#include <math.h>

// Problem constants (from reference setup_inputs)
#define NB 2
#define SEQ 2048
#define NH 16
#define DNOPE 128
#define DROT 64
#define DVDIM 128
#define DQK 192
#define BM 64
#define BN 64

typedef __bf16 bf16x8_t __attribute__((ext_vector_type(8)));
typedef float f32x4_t __attribute__((ext_vector_type(4)));

// log2(10000)/32 — inv_freq_i = 2^(-i * this); YaRN collapses (SCALING_FACTOR==1)
#define LOG2_BASE_OVER_HALFDIM 0.41524101186092028f
// 192^-0.5 * log2(e), folded into Q at bf16-convert time
#define KSL2 0.10412340175817158f

// ws layout
#define KBF_ELEMS   ((size_t)NB * NH * SEQ * DQK)          // 12,582,912
#define KPREP_BLOCKS 6144                                  // KBF_ELEMS/8/256
#define VPREP_BLOCKS 1024                                  // 32*16*2

// ---------------------------------------------------------------------------
// Fused prep: blocks [0,6144) build K bf16 [b][h][s][192] = concat(k_nope,
// rope(k_pe)); blocks [6144,7168) build V bf16 transposed [b][h][dv][s].
// Trig inline via libm sincosf (full range reduction; args <= ~2047).
// ---------------------------------------------------------------------------
__global__ __launch_bounds__(256) void prep_kernel(
    const float* __restrict__ k_nope, const float* __restrict__ k_pe,
    const float* __restrict__ v, __bf16* __restrict__ Kbf,
    __bf16* __restrict__ Vtb) {
  __shared__ __bf16 T[64][130];
  const int bid = blockIdx.x;
  const int tid = threadIdx.x;
  if (bid < KPREP_BLOCKS) {
    int gid = bid * 256 + tid;                  // 8 elems each
    size_t o8 = (size_t)gid * 8;
    int d0 = (int)(o8 % DQK);                   // multiple of 8
    int rest = (int)(o8 / DQK);                 // (b*16+h)*2048 + s
    int s = rest & (SEQ - 1);
    int bh = rest >> 11;
    int h = bh & (NH - 1), b = bh >> 4;
    bf16x8_t o;
    if (d0 < DNOPE) {
      const float* p = k_nope + ((size_t)((b * SEQ + s) * NH + h)) * DNOPE + d0;
      float4 a = *(const float4*)p;
      float4 c = *(const float4*)(p + 4);
      o[0] = (__bf16)a.x; o[1] = (__bf16)a.y; o[2] = (__bf16)a.z; o[3] = (__bf16)a.w;
      o[4] = (__bf16)c.x; o[5] = (__bf16)c.y; o[6] = (__bf16)c.z; o[7] = (__bf16)c.w;
    } else {
      int dr0 = d0 - DNOPE;
      const float* p = k_pe + (size_t)(b * SEQ + s) * DROT;
#pragma unroll
      for (int j = 0; j < 8; ++j) {
        int dr = dr0 + j;
        int i = dr & 31;
        float invf = exp2f(-LOG2_BASE_OVER_HALFDIM * (float)i);
        float ang = (float)s * invf;
        float sn, cs; sincosf(ang, &sn, &cs);
        float x = p[dr];
        float oth = (dr < 32) ? -p[dr + 32] : p[dr - 32];
        o[j] = (__bf16)(x * cs + oth * sn);
      }
    }
    *(bf16x8_t*)&Kbf[o8] = o;
  } else {
    int vb = bid - KPREP_BLOCKS;
    const int s0 = (vb & 31) * 64, h = (vb >> 5) & (NH - 1), b = vb >> 9;
#pragma unroll
    for (int r = 0; r < 8; ++r) {
      int task = tid + r * 256;                 // 0..2047
      int srow = task >> 5, c4 = (task & 31) * 4;
      const float* p = v + ((size_t)((b * SEQ + s0 + srow) * NH + h)) * DVDIM + c4;
      float4 a = *(const float4*)p;
      T[srow][c4 + 0] = (__bf16)a.x; T[srow][c4 + 1] = (__bf16)a.y;
      T[srow][c4 + 2] = (__bf16)a.z; T[srow][c4 + 3] = (__bf16)a.w;
    }
    __syncthreads();
#pragma unroll
    for (int r = 0; r < 4; ++r) {
      int task = tid + r * 256;                 // 0..1023
      int dv = task >> 3, c8 = (task & 7) * 8;
      bf16x8_t o;
#pragma unroll
      for (int u = 0; u < 8; ++u) o[u] = T[c8 + u][dv];
      *(bf16x8_t*)&Vtb[((size_t)(b * NH + h) * DVDIM + dv) * SEQ + s0 + c8] = o;
    }
  }
}

// ---------------------------------------------------------------------------
// Flash attention fwd. Grid (1024): ONE q-tile per WG (vs the old paired
// scheme). bid%8 selects the XCD (round-robin heuristic); each XCD owns 4
// fixed (b,h) slabs so K/V re-reads hit that XCD's L2. qt is ordered
// DESCENDING with bid so the longest WGs (qt=31, 32 k-iters) dispatch first
// and the backfill tail is the short ones -> load balance without pairing.
// 1024 WGs / 256 CUs + LDS 48 KiB -> 3 blocks/CU resident (was 2), giving a
// third independent instruction stream per SIMD to hide the per-iteration
// serial chain (QK MFMA -> softmax VALU -> P LDS -> PV MFMA, 2 barriers).
// Register-prefetch pipeline: tile it+1 is loaded into VGPRs while tile it
// is computed; LDS commit is 10 ds_write_b128 between the two barriers.
// LDS tiles are 16B blocks with XOR swizzle (all MFMA ds_read_b128 2-way/free).
// l is accumulated by MFMA against a ones B-fragment (flash l recurrence ==
// extra output column); the ones frag is (col==0)?1:0 built in registers.
// ---------------------------------------------------------------------------
__global__ __launch_bounds__(256, 3) void mla_fwd_kernel(
    const float* __restrict__ q_nope, const float* __restrict__ q_pe,
    const __bf16* __restrict__ Kbf, const __bf16* __restrict__ Vtb,
    float* __restrict__ out_o, float* __restrict__ out_lse) {
  __shared__ __bf16 Kl[BN * DQK];       // 24576 B
  __shared__ __bf16 Vl[DVDIM * BN];     // 16384 B
  __shared__ __bf16 Pl[4 * 16 * BN];    //  8192 B   (total 49152 B -> 3 blocks/CU)

  // ---- decode grid: xcd-clustered slabs, globally descending qt
  const int bid = blockIdx.x;           // 0..1023
  const int xcd = bid & 7;
  const int j   = bid >> 3;             // 0..127
  const int sl  = j & 3;                // slab-local 0..3
  const int qt  = 31 - (j >> 2);        // 31..0 (long WGs dispatch first)
  const int g   = sl * 8 + xcd;         // slab id 0..31
  const int h   = g & (NH - 1), b = g >> 4;

  const int tid = threadIdx.x;
  const int w = tid >> 6, lane = tid & 63;
  const int col = lane & 15, quad = lane >> 4;
  const int swz = col & 7;
  const int e0 = quad ^ swz, e1 = (quad + 4) ^ swz;   // swizzled block slots

  // ones B-fragment for the l-column MFMA: B[k][n] = (n==0)
  const __bf16 onev = (col == 0) ? (__bf16)1.0f : (__bf16)0.0f;
  bf16x8_t vxf;
#pragma unroll
  for (int u = 0; u < 8; ++u) vxf[u] = onev;

  const __bf16* Kslab = Kbf + (size_t)(b * NH + h) * SEQ * DQK;
  const __bf16* Vslab = Vtb + (size_t)(b * NH + h) * DVDIM * SEQ;

  // staging source offsets (swizzle folded into global source index)
  int kofs[6];
#pragma unroll
  for (int r = 0; r < 6; ++r) {
    int L = r * 256 + tid;                 // linear 16B block 0..1535
    int n = L / 24, jj = L - n * 24;
    int jsrc = (jj & ~7) | ((jj & 7) ^ (n & 7));
    kofs[r] = n * DQK + jsrc * 8;
  }
  int vofs[4];
#pragma unroll
  for (int r = 0; r < 4; ++r) {
    int L = r * 256 + tid;                 // 0..1023
    int dv = L >> 3, jj = L & 7;
    vofs[r] = dv * SEQ + (jj ^ (dv & 7)) * 8;
  }

  const int qb = qt * BM;
  const int mrow = qb + w * 16 + col;

  // ---- Q fragments (A-layout: A[m=lane&15][k=quad*8+j]); scale folded in;
  // rope chunks 4,5 computed with inline sincosf (8 calls, once per WG).
  const float* qn = q_nope + (size_t)((b * SEQ + mrow) * NH + h) * DNOPE;
  const float* qp = q_pe   + (size_t)((b * SEQ + mrow) * NH + h) * DROT;
  bf16x8_t qfrag[6];
#pragma unroll
  for (int c = 0; c < 4; ++c) {
    const float* p = qn + c * 32 + quad * 8;
    float4 a = *(const float4*)p;
    float4 bq = *(const float4*)(p + 4);
    bf16x8_t f;
    f[0]=(__bf16)(a.x*KSL2);  f[1]=(__bf16)(a.y*KSL2);
    f[2]=(__bf16)(a.z*KSL2);  f[3]=(__bf16)(a.w*KSL2);
    f[4]=(__bf16)(bq.x*KSL2); f[5]=(__bf16)(bq.y*KSL2);
    f[6]=(__bf16)(bq.z*KSL2); f[7]=(__bf16)(bq.w*KSL2);
    qfrag[c] = f;
  }
  {
    const float* plo = qp + quad * 8;
    const float* phi = qp + 32 + quad * 8;
    float4 lo0 = *(const float4*)plo;
    float4 lo1 = *(const float4*)(plo + 4);
    float4 hi0 = *(const float4*)phi;
    float4 hi1 = *(const float4*)(phi + 4);
    float xl[8] = {lo0.x,lo0.y,lo0.z,lo0.w,lo1.x,lo1.y,lo1.z,lo1.w};
    float xh[8] = {hi0.x,hi0.y,hi0.z,hi0.w,hi1.x,hi1.y,hi1.z,hi1.w};
    bf16x8_t f4v, f5v;
#pragma unroll
    for (int jr = 0; jr < 8; ++jr) {
      int i = quad * 8 + jr;
      float invf = exp2f(-LOG2_BASE_OVER_HALFDIM * (float)i);
      float ang = (float)mrow * invf;
      float sn, cs; sincosf(ang, &sn, &cs);
      f4v[jr] = (__bf16)((xl[jr] * cs - xh[jr] * sn) * KSL2);
      f5v[jr] = (__bf16)((xh[jr] * cs + xl[jr] * sn) * KSL2);
    }
    qfrag[4] = f4v; qfrag[5] = f5v;
  }

  f32x4_t oacc[8];
#pragma unroll
  for (int i = 0; i < 8; ++i) oacc[i] = (f32x4_t){0.f, 0.f, 0.f, 0.f};
  f32x4_t lacc = (f32x4_t){0.f, 0.f, 0.f, 0.f};
  float m_run[4] = {-INFINITY, -INFINITY, -INFINITY, -INFINITY};

  // ---- prologue: load tile 0 into registers
  bf16x8_t Kreg[6], Vreg[4];
#pragma unroll
  for (int r = 0; r < 6; ++r) Kreg[r] = *(const bf16x8_t*)(Kslab + kofs[r]);
#pragma unroll
  for (int r = 0; r < 4; ++r) Vreg[r] = *(const bf16x8_t*)(Vslab + vofs[r]);

  for (int it = 0; it <= qt; ++it) {
    __syncthreads();                     // prev readers done before overwrite
    // commit registers to LDS (10 x ds_write_b128, conflict-free)
#pragma unroll
    for (int r = 0; r < 6; ++r) *(bf16x8_t*)&Kl[(r * 256 + tid) * 8] = Kreg[r];
#pragma unroll
    for (int r = 0; r < 4; ++r) *(bf16x8_t*)&Vl[(r * 256 + tid) * 8] = Vreg[r];
    __syncthreads();                     // writes visible
    // prefetch tile it+1 (latency overlaps the whole compute phase)
    if (it < qt) {
      const __bf16* Ksrc = Kslab + (size_t)(it + 1) * BN * DQK;
      const __bf16* Vsrc = Vslab + (it + 1) * BN;
#pragma unroll
      for (int r = 0; r < 6; ++r) Kreg[r] = *(const bf16x8_t*)(Ksrc + kofs[r]);
#pragma unroll
      for (int r = 0; r < 4; ++r) Vreg[r] = *(const bf16x8_t*)(Vsrc + vofs[r]);
    }

    // ---- S = Q K^T : 4 n-tiles, 6 K-chunks (pre-scaled, log2 domain)
    f32x4_t sacc[4];
#pragma unroll
    for (int t = 0; t < 4; ++t) sacc[t] = (f32x4_t){0.f, 0.f, 0.f, 0.f};
#pragma unroll
    for (int t = 0; t < 4; ++t) {
      const __bf16* kr = &Kl[(t * 16 + col) * 24 * 8];
      sacc[t] = __builtin_amdgcn_mfma_f32_16x16x32_bf16(qfrag[0], *(const bf16x8_t*)&kr[e0 * 8], sacc[t], 0, 0, 0);
      sacc[t] = __builtin_amdgcn_mfma_f32_16x16x32_bf16(qfrag[1], *(const bf16x8_t*)&kr[e1 * 8], sacc[t], 0, 0, 0);
      sacc[t] = __builtin_amdgcn_mfma_f32_16x16x32_bf16(qfrag[2], *(const bf16x8_t*)&kr[64 + e0 * 8], sacc[t], 0, 0, 0);
      sacc[t] = __builtin_amdgcn_mfma_f32_16x16x32_bf16(qfrag[3], *(const bf16x8_t*)&kr[64 + e1 * 8], sacc[t], 0, 0, 0);
      sacc[t] = __builtin_amdgcn_mfma_f32_16x16x32_bf16(qfrag[4], *(const bf16x8_t*)&kr[128 + e0 * 8], sacc[t], 0, 0, 0);
      sacc[t] = __builtin_amdgcn_mfma_f32_16x16x32_bf16(qfrag[5], *(const bf16x8_t*)&kr[128 + e1 * 8], sacc[t], 0, 0, 0);
    }

    // ---- online softmax (log2 domain; only the max needs a reduction)
    const bool diag = (it == qt);
    float pv[4][4];
    float alpha[4];
#pragma unroll
    for (int r = 0; r < 4; ++r) {
      float mx = -INFINITY;
#pragma unroll
      for (int t = 0; t < 4; ++t) {
        float sv = sacc[t][r];
        if (diag) {
          int nn = (qt << 6) + t * 16 + col;
          int mm = qb + w * 16 + quad * 4 + r;
          if (nn > mm) sv = -INFINITY;
        }
        pv[t][r] = sv;
        mx = fmaxf(mx, sv);
      }
      mx = fmaxf(mx, __shfl_xor(mx, 1, 64));
      mx = fmaxf(mx, __shfl_xor(mx, 2, 64));
      mx = fmaxf(mx, __shfl_xor(mx, 4, 64));
      mx = fmaxf(mx, __shfl_xor(mx, 8, 64));
      float mnew = fmaxf(m_run[r], mx);
      alpha[r] = exp2f(m_run[r] - mnew);
      m_run[r] = mnew;
#pragma unroll
      for (int t = 0; t < 4; ++t) pv[t][r] = exp2f(pv[t][r] - mnew);
    }
#pragma unroll
    for (int d = 0; d < 8; ++d) {
      f32x4_t o = oacc[d];
      o[0] *= alpha[0]; o[1] *= alpha[1]; o[2] *= alpha[2]; o[3] *= alpha[3];
      oacc[d] = o;
    }
    lacc[0] *= alpha[0]; lacc[1] *= alpha[1];
    lacc[2] *= alpha[2]; lacc[3] *= alpha[3];

    // ---- P: C-layout regs -> swizzled per-wave LDS -> A-layout frags
    __bf16* Pw = &Pl[w * 16 * BN];
#pragma unroll
    for (int t = 0; t < 4; ++t)
#pragma unroll
      for (int r = 0; r < 4; ++r) {
        int row = quad * 4 + r;
        int jj = t * 2 + (col >> 3);
        Pw[(row * 8 + (jj ^ (row & 7))) * 8 + (col & 7)] = (__bf16)pv[t][r];
      }
    bf16x8_t pf0 = *(const bf16x8_t*)&Pw[(col * 8 + e0) * 8];
    bf16x8_t pf1 = *(const bf16x8_t*)&Pw[(col * 8 + e1) * 8];

    // ---- O += P V ; l += P * ones (extra static column)
#pragma unroll
    for (int d = 0; d < 8; ++d) {
      const __bf16* vr = &Vl[(d * 16 + col) * 64];
      bf16x8_t vf0 = *(const bf16x8_t*)&vr[e0 * 8];
      bf16x8_t vf1 = *(const bf16x8_t*)&vr[e1 * 8];
      oacc[d] = __builtin_amdgcn_mfma_f32_16x16x32_bf16(pf0, vf0, oacc[d], 0, 0, 0);
      oacc[d] = __builtin_amdgcn_mfma_f32_16x16x32_bf16(pf1, vf1, oacc[d], 0, 0, 0);
    }
    lacc = __builtin_amdgcn_mfma_f32_16x16x32_bf16(pf0, vxf, lacc, 0, 0, 0);
    lacc = __builtin_amdgcn_mfma_f32_16x16x32_bf16(pf1, vxf, lacc, 0, 0, 0);
  }

  // ---- epilogue: broadcast l from col-0 lanes, normalize, store
  float lr[4];
#pragma unroll
  for (int r = 0; r < 4; ++r) lr[r] = __shfl(lacc[r], lane & 48, 64);
  float inv_l[4];
#pragma unroll
  for (int r = 0; r < 4; ++r) inv_l[r] = 1.0f / lr[r];
#pragma unroll
  for (int d = 0; d < 8; ++d) {
#pragma unroll
    for (int r = 0; r < 4; ++r) {
      int mm = qb + w * 16 + quad * 4 + r;
      out_o[(size_t)((b * SEQ + mm) * NH + h) * DVDIM + d * 16 + col] = oacc[d][r] * inv_l[r];
    }
  }
  if (col < 4) {
    int r = col;
    int mm = qb + w * 16 + quad * 4 + r;
    out_lse[(size_t)(b * SEQ + mm) * NH + h] = m_run[r] + log2f(lr[r]);
  }
}

// ---------------------------------------------------------------------------
extern "C" void kernel_launch(void* const* d_in, const int* in_sizes, int n_in,
                              void* d_out, int out_size, void* d_ws, size_t ws_size,
                              hipStream_t stream) {
  const float* q_nope = (const float*)d_in[0];
  const float* q_pe   = (const float*)d_in[1];
  const float* k_nope = (const float*)d_in[2];
  const float* k_pe   = (const float*)d_in[3];
  const float* v      = (const float*)d_in[4];
  float* out_o   = (float*)d_out;
  float* out_lse = out_o + (size_t)NB * SEQ * NH * DVDIM;

  __bf16* Kbf = (__bf16*)d_ws;
  __bf16* Vtb = Kbf + KBF_ELEMS;   // total ws use ~40 MB

  prep_kernel<<<dim3(KPREP_BLOCKS + VPREP_BLOCKS), dim3(256), 0, stream>>>(
      k_nope, k_pe, v, Kbf, Vtb);
  mla_fwd_kernel<<<dim3(1024), dim3(256), 0, stream>>>(
      q_nope, q_pe, Kbf, Vtb, out_o, out_lse);
}

// Round 3
// 273.518 us; speedup vs baseline: 1.0526x; 1.0526x over previous
//
#include <hip/hip_runtime.h>
#include <hip/hip_bf16.h>
#include <math.h>

// Problem constants (from reference setup_inputs)
#define NB 2
#define SEQ 2048
#define NH 16
#define DNOPE 128
#define DROT 64
#define DVDIM 128
#define DQK 192
#define BM 64
#define BN 64

typedef __bf16 bf16x8_t __attribute__((ext_vector_type(8)));
typedef float f32x4_t __attribute__((ext_vector_type(4)));

// log2(10000)/32 — inv_freq_i = 2^(-i * this); YaRN collapses (SCALING_FACTOR==1)
#define LOG2_BASE_OVER_HALFDIM 0.41524101186092028f
// 192^-0.5 * log2(e), folded into Q at bf16-convert time
#define KSL2 0.10412340175817158f

// ws layout
#define KBF_ELEMS   ((size_t)NB * NH * SEQ * DQK)          // 12,582,912
#define KPREP_BLOCKS 6144                                  // KBF_ELEMS/8/256
#define VPREP_BLOCKS 1024                                  // 32*16*2

// ---------------------------------------------------------------------------
// Fused prep: blocks [0,6144) build K bf16 [b][h][s][192] = concat(k_nope,
// rope(k_pe)); blocks [6144,7168) build V bf16 transposed [b][h][dv][s].
// Trig inline via libm sincosf (full range reduction; args <= ~2047).
// ---------------------------------------------------------------------------
__global__ __launch_bounds__(256) void prep_kernel(
    const float* __restrict__ k_nope, const float* __restrict__ k_pe,
    const float* __restrict__ v, __bf16* __restrict__ Kbf,
    __bf16* __restrict__ Vtb) {
  __shared__ __bf16 T[64][130];
  const int bid = blockIdx.x;
  const int tid = threadIdx.x;
  if (bid < KPREP_BLOCKS) {
    int gid = bid * 256 + tid;                  // 8 elems each
    size_t o8 = (size_t)gid * 8;
    int d0 = (int)(o8 % DQK);                   // multiple of 8
    int rest = (int)(o8 / DQK);                 // (b*16+h)*2048 + s
    int s = rest & (SEQ - 1);
    int bh = rest >> 11;
    int h = bh & (NH - 1), b = bh >> 4;
    bf16x8_t o;
    if (d0 < DNOPE) {
      const float* p = k_nope + ((size_t)((b * SEQ + s) * NH + h)) * DNOPE + d0;
      float4 a = *(const float4*)p;
      float4 c = *(const float4*)(p + 4);
      o[0] = (__bf16)a.x; o[1] = (__bf16)a.y; o[2] = (__bf16)a.z; o[3] = (__bf16)a.w;
      o[4] = (__bf16)c.x; o[5] = (__bf16)c.y; o[6] = (__bf16)c.z; o[7] = (__bf16)c.w;
    } else {
      int dr0 = d0 - DNOPE;
      const float* p = k_pe + (size_t)(b * SEQ + s) * DROT;
#pragma unroll
      for (int j = 0; j < 8; ++j) {
        int dr = dr0 + j;
        int i = dr & 31;
        float invf = exp2f(-LOG2_BASE_OVER_HALFDIM * (float)i);
        float ang = (float)s * invf;
        float sn, cs; sincosf(ang, &sn, &cs);
        float x = p[dr];
        float oth = (dr < 32) ? -p[dr + 32] : p[dr - 32];
        o[j] = (__bf16)(x * cs + oth * sn);
      }
    }
    *(bf16x8_t*)&Kbf[o8] = o;
  } else {
    int vb = bid - KPREP_BLOCKS;
    const int s0 = (vb & 31) * 64, h = (vb >> 5) & (NH - 1), b = vb >> 9;
#pragma unroll
    for (int r = 0; r < 8; ++r) {
      int task = tid + r * 256;                 // 0..2047
      int srow = task >> 5, c4 = (task & 31) * 4;
      const float* p = v + ((size_t)((b * SEQ + s0 + srow) * NH + h)) * DVDIM + c4;
      float4 a = *(const float4*)p;
      T[srow][c4 + 0] = (__bf16)a.x; T[srow][c4 + 1] = (__bf16)a.y;
      T[srow][c4 + 2] = (__bf16)a.z; T[srow][c4 + 3] = (__bf16)a.w;
    }
    __syncthreads();
#pragma unroll
    for (int r = 0; r < 4; ++r) {
      int task = tid + r * 256;                 // 0..1023
      int dv = task >> 3, c8 = (task & 7) * 8;
      bf16x8_t o;
#pragma unroll
      for (int u = 0; u < 8; ++u) o[u] = T[c8 + u][dv];
      *(bf16x8_t*)&Vtb[((size_t)(b * NH + h) * DVDIM + dv) * SEQ + s0 + c8] = o;
    }
  }
}

// ---------------------------------------------------------------------------
// Flash attention fwd. Grid (1024): ONE q-tile per WG. bid%8 selects the XCD
// (round-robin dispatch heuristic); each XCD owns 4 fixed (b,h) slabs so K/V
// re-reads hit that XCD's L2 (validated round 1: FETCH_SIZE 259->89 MB).
// qt is ordered DESCENDING with bid so the longest WGs (qt=31, 32 k-iters)
// dispatch first and the backfill tail is the short ones.
// LDS 48 KiB -> 3 blocks/CU resident; VGPR must stay <=128 for 4 waves/SIMD.
// __launch_bounds__(256, 2): round 1 showed (256,3) strangles the allocator
// to 84 VGPRs -> scratch spills in the k-loop (+64 MB writeback, -20% perf).
// (256,2) compiles to ~120 VGPR, zero spills; residency is resource-limited
// to 3 blocks/CU anyway (grid supplies it).
// Register-prefetch pipeline: tile it+1 is loaded into VGPRs while tile it
// is computed; LDS commit is 10 ds_write_b128 between the two barriers.
// LDS tiles are 16B blocks with XOR swizzle (all MFMA ds_read_b128 2-way/free).
// l is accumulated by MFMA against a ones B-fragment (flash l recurrence ==
// extra output column); the ones frag is (col==0)?1:0 built in registers.
// ---------------------------------------------------------------------------
__global__ __launch_bounds__(256, 2) void mla_fwd_kernel(
    const float* __restrict__ q_nope, const float* __restrict__ q_pe,
    const __bf16* __restrict__ Kbf, const __bf16* __restrict__ Vtb,
    float* __restrict__ out_o, float* __restrict__ out_lse) {
  __shared__ __bf16 Kl[BN * DQK];       // 24576 B
  __shared__ __bf16 Vl[DVDIM * BN];     // 16384 B
  __shared__ __bf16 Pl[4 * 16 * BN];    //  8192 B   (total 49152 B -> 3 blocks/CU)

  // ---- decode grid: xcd-clustered slabs, globally descending qt
  const int bid = blockIdx.x;           // 0..1023
  const int xcd = bid & 7;
  const int j   = bid >> 3;             // 0..127
  const int sl  = j & 3;                // slab-local 0..3
  const int qt  = 31 - (j >> 2);        // 31..0 (long WGs dispatch first)
  const int g   = sl * 8 + xcd;         // slab id 0..31
  const int h   = g & (NH - 1), b = g >> 4;

  const int tid = threadIdx.x;
  const int w = tid >> 6, lane = tid & 63;
  const int col = lane & 15, quad = lane >> 4;
  const int swz = col & 7;
  const int e0 = quad ^ swz, e1 = (quad + 4) ^ swz;   // swizzled block slots

  // ones B-fragment for the l-column MFMA: B[k][n] = (n==0)
  const __bf16 onev = (col == 0) ? (__bf16)1.0f : (__bf16)0.0f;
  bf16x8_t vxf;
#pragma unroll
  for (int u = 0; u < 8; ++u) vxf[u] = onev;

  const __bf16* Kslab = Kbf + (size_t)(b * NH + h) * SEQ * DQK;
  const __bf16* Vslab = Vtb + (size_t)(b * NH + h) * DVDIM * SEQ;

  // staging source offsets (swizzle folded into global source index)
  int kofs[6];
#pragma unroll
  for (int r = 0; r < 6; ++r) {
    int L = r * 256 + tid;                 // linear 16B block 0..1535
    int n = L / 24, jj = L - n * 24;
    int jsrc = (jj & ~7) | ((jj & 7) ^ (n & 7));
    kofs[r] = n * DQK + jsrc * 8;
  }
  int vofs[4];
#pragma unroll
  for (int r = 0; r < 4; ++r) {
    int L = r * 256 + tid;                 // 0..1023
    int dv = L >> 3, jj = L & 7;
    vofs[r] = dv * SEQ + (jj ^ (dv & 7)) * 8;
  }

  const int qb = qt * BM;
  const int mrow = qb + w * 16 + col;

  // ---- Q fragments (A-layout: A[m=lane&15][k=quad*8+j]); scale folded in;
  // rope chunks 4,5 computed with inline sincosf (8 calls, once per WG).
  const float* qn = q_nope + (size_t)((b * SEQ + mrow) * NH + h) * DNOPE;
  const float* qp = q_pe   + (size_t)((b * SEQ + mrow) * NH + h) * DROT;
  bf16x8_t qfrag[6];
#pragma unroll
  for (int c = 0; c < 4; ++c) {
    const float* p = qn + c * 32 + quad * 8;
    float4 a = *(const float4*)p;
    float4 bq = *(const float4*)(p + 4);
    bf16x8_t f;
    f[0]=(__bf16)(a.x*KSL2);  f[1]=(__bf16)(a.y*KSL2);
    f[2]=(__bf16)(a.z*KSL2);  f[3]=(__bf16)(a.w*KSL2);
    f[4]=(__bf16)(bq.x*KSL2); f[5]=(__bf16)(bq.y*KSL2);
    f[6]=(__bf16)(bq.z*KSL2); f[7]=(__bf16)(bq.w*KSL2);
    qfrag[c] = f;
  }
  {
    const float* plo = qp + quad * 8;
    const float* phi = qp + 32 + quad * 8;
    float4 lo0 = *(const float4*)plo;
    float4 lo1 = *(const float4*)(plo + 4);
    float4 hi0 = *(const float4*)phi;
    float4 hi1 = *(const float4*)(phi + 4);
    float xl[8] = {lo0.x,lo0.y,lo0.z,lo0.w,lo1.x,lo1.y,lo1.z,lo1.w};
    float xh[8] = {hi0.x,hi0.y,hi0.z,hi0.w,hi1.x,hi1.y,hi1.z,hi1.w};
    bf16x8_t f4v, f5v;
#pragma unroll
    for (int jr = 0; jr < 8; ++jr) {
      int i = quad * 8 + jr;
      float invf = exp2f(-LOG2_BASE_OVER_HALFDIM * (float)i);
      float ang = (float)mrow * invf;
      float sn, cs; sincosf(ang, &sn, &cs);
      f4v[jr] = (__bf16)((xl[jr] * cs - xh[jr] * sn) * KSL2);
      f5v[jr] = (__bf16)((xh[jr] * cs + xl[jr] * sn) * KSL2);
    }
    qfrag[4] = f4v; qfrag[5] = f5v;
  }

  f32x4_t oacc[8];
#pragma unroll
  for (int i = 0; i < 8; ++i) oacc[i] = (f32x4_t){0.f, 0.f, 0.f, 0.f};
  f32x4_t lacc = (f32x4_t){0.f, 0.f, 0.f, 0.f};
  float m_run[4] = {-INFINITY, -INFINITY, -INFINITY, -INFINITY};

  // ---- prologue: load tile 0 into registers
  bf16x8_t Kreg[6], Vreg[4];
#pragma unroll
  for (int r = 0; r < 6; ++r) Kreg[r] = *(const bf16x8_t*)(Kslab + kofs[r]);
#pragma unroll
  for (int r = 0; r < 4; ++r) Vreg[r] = *(const bf16x8_t*)(Vslab + vofs[r]);

  for (int it = 0; it <= qt; ++it) {
    __syncthreads();                     // prev readers done before overwrite
    // commit registers to LDS (10 x ds_write_b128, conflict-free)
#pragma unroll
    for (int r = 0; r < 6; ++r) *(bf16x8_t*)&Kl[(r * 256 + tid) * 8] = Kreg[r];
#pragma unroll
    for (int r = 0; r < 4; ++r) *(bf16x8_t*)&Vl[(r * 256 + tid) * 8] = Vreg[r];
    __syncthreads();                     // writes visible
    // prefetch tile it+1 (latency overlaps the whole compute phase)
    if (it < qt) {
      const __bf16* Ksrc = Kslab + (size_t)(it + 1) * BN * DQK;
      const __bf16* Vsrc = Vslab + (it + 1) * BN;
#pragma unroll
      for (int r = 0; r < 6; ++r) Kreg[r] = *(const bf16x8_t*)(Ksrc + kofs[r]);
#pragma unroll
      for (int r = 0; r < 4; ++r) Vreg[r] = *(const bf16x8_t*)(Vsrc + vofs[r]);
    }

    // ---- S = Q K^T : 4 n-tiles, 6 K-chunks (pre-scaled, log2 domain)
    f32x4_t sacc[4];
#pragma unroll
    for (int t = 0; t < 4; ++t) sacc[t] = (f32x4_t){0.f, 0.f, 0.f, 0.f};
#pragma unroll
    for (int t = 0; t < 4; ++t) {
      const __bf16* kr = &Kl[(t * 16 + col) * 24 * 8];
      sacc[t] = __builtin_amdgcn_mfma_f32_16x16x32_bf16(qfrag[0], *(const bf16x8_t*)&kr[e0 * 8], sacc[t], 0, 0, 0);
      sacc[t] = __builtin_amdgcn_mfma_f32_16x16x32_bf16(qfrag[1], *(const bf16x8_t*)&kr[e1 * 8], sacc[t], 0, 0, 0);
      sacc[t] = __builtin_amdgcn_mfma_f32_16x16x32_bf16(qfrag[2], *(const bf16x8_t*)&kr[64 + e0 * 8], sacc[t], 0, 0, 0);
      sacc[t] = __builtin_amdgcn_mfma_f32_16x16x32_bf16(qfrag[3], *(const bf16x8_t*)&kr[64 + e1 * 8], sacc[t], 0, 0, 0);
      sacc[t] = __builtin_amdgcn_mfma_f32_16x16x32_bf16(qfrag[4], *(const bf16x8_t*)&kr[128 + e0 * 8], sacc[t], 0, 0, 0);
      sacc[t] = __builtin_amdgcn_mfma_f32_16x16x32_bf16(qfrag[5], *(const bf16x8_t*)&kr[128 + e1 * 8], sacc[t], 0, 0, 0);
    }

    // ---- online softmax (log2 domain; only the max needs a reduction)
    const bool diag = (it == qt);
    float pv[4][4];
    float alpha[4];
#pragma unroll
    for (int r = 0; r < 4; ++r) {
      float mx = -INFINITY;
#pragma unroll
      for (int t = 0; t < 4; ++t) {
        float sv = sacc[t][r];
        if (diag) {
          int nn = (qt << 6) + t * 16 + col;
          int mm = qb + w * 16 + quad * 4 + r;
          if (nn > mm) sv = -INFINITY;
        }
        pv[t][r] = sv;
        mx = fmaxf(mx, sv);
      }
      mx = fmaxf(mx, __shfl_xor(mx, 1, 64));
      mx = fmaxf(mx, __shfl_xor(mx, 2, 64));
      mx = fmaxf(mx, __shfl_xor(mx, 4, 64));
      mx = fmaxf(mx, __shfl_xor(mx, 8, 64));
      float mnew = fmaxf(m_run[r], mx);
      alpha[r] = exp2f(m_run[r] - mnew);
      m_run[r] = mnew;
#pragma unroll
      for (int t = 0; t < 4; ++t) pv[t][r] = exp2f(pv[t][r] - mnew);
    }
#pragma unroll
    for (int d = 0; d < 8; ++d) {
      f32x4_t o = oacc[d];
      o[0] *= alpha[0]; o[1] *= alpha[1]; o[2] *= alpha[2]; o[3] *= alpha[3];
      oacc[d] = o;
    }
    lacc[0] *= alpha[0]; lacc[1] *= alpha[1];
    lacc[2] *= alpha[2]; lacc[3] *= alpha[3];

    // ---- P: C-layout regs -> swizzled per-wave LDS -> A-layout frags
    __bf16* Pw = &Pl[w * 16 * BN];
#pragma unroll
    for (int t = 0; t < 4; ++t)
#pragma unroll
      for (int r = 0; r < 4; ++r) {
        int row = quad * 4 + r;
        int jj = t * 2 + (col >> 3);
        Pw[(row * 8 + (jj ^ (row & 7))) * 8 + (col & 7)] = (__bf16)pv[t][r];
      }
    bf16x8_t pf0 = *(const bf16x8_t*)&Pw[(col * 8 + e0) * 8];
    bf16x8_t pf1 = *(const bf16x8_t*)&Pw[(col * 8 + e1) * 8];

    // ---- O += P V ; l += P * ones (extra static column)
#pragma unroll
    for (int d = 0; d < 8; ++d) {
      const __bf16* vr = &Vl[(d * 16 + col) * 64];
      bf16x8_t vf0 = *(const bf16x8_t*)&vr[e0 * 8];
      bf16x8_t vf1 = *(const bf16x8_t*)&vr[e1 * 8];
      oacc[d] = __builtin_amdgcn_mfma_f32_16x16x32_bf16(pf0, vf0, oacc[d], 0, 0, 0);
      oacc[d] = __builtin_amdgcn_mfma_f32_16x16x32_bf16(pf1, vf1, oacc[d], 0, 0, 0);
    }
    lacc = __builtin_amdgcn_mfma_f32_16x16x32_bf16(pf0, vxf, lacc, 0, 0, 0);
    lacc = __builtin_amdgcn_mfma_f32_16x16x32_bf16(pf1, vxf, lacc, 0, 0, 0);
  }

  // ---- epilogue: broadcast l from col-0 lanes, normalize, store
  float lr[4];
#pragma unroll
  for (int r = 0; r < 4; ++r) lr[r] = __shfl(lacc[r], lane & 48, 64);
  float inv_l[4];
#pragma unroll
  for (int r = 0; r < 4; ++r) inv_l[r] = 1.0f / lr[r];
#pragma unroll
  for (int d = 0; d < 8; ++d) {
#pragma unroll
    for (int r = 0; r < 4; ++r) {
      int mm = qb + w * 16 + quad * 4 + r;
      out_o[(size_t)((b * SEQ + mm) * NH + h) * DVDIM + d * 16 + col] = oacc[d][r] * inv_l[r];
    }
  }
  if (col < 4) {
    int r = col;
    int mm = qb + w * 16 + quad * 4 + r;
    out_lse[(size_t)(b * SEQ + mm) * NH + h] = m_run[r] + log2f(lr[r]);
  }
}

// ---------------------------------------------------------------------------
extern "C" void kernel_launch(void* const* d_in, const int* in_sizes, int n_in,
                              void* d_out, int out_size, void* d_ws, size_t ws_size,
                              hipStream_t stream) {
  const float* q_nope = (const float*)d_in[0];
  const float* q_pe   = (const float*)d_in[1];
  const float* k_nope = (const float*)d_in[2];
  const float* k_pe   = (const float*)d_in[3];
  const float* v      = (const float*)d_in[4];
  float* out_o   = (float*)d_out;
  float* out_lse = out_o + (size_t)NB * SEQ * NH * DVDIM;

  __bf16* Kbf = (__bf16*)d_ws;
  __bf16* Vtb = Kbf + KBF_ELEMS;   // total ws use ~40 MB

  prep_kernel<<<dim3(KPREP_BLOCKS + VPREP_BLOCKS), dim3(256), 0, stream>>>(
      k_nope, k_pe, v, Kbf, Vtb);
  mla_fwd_kernel<<<dim3(1024), dim3(256), 0, stream>>>(
      q_nope, q_pe, Kbf, Vtb, out_o, out_lse);
}

// Round 5
// 248.540 us; speedup vs baseline: 1.1584x; 1.1005x over previous
//
#include <hip/hip_runtime.h>
#include <hip/hip_bf16.h>
#include <math.h>

// Problem constants (from reference setup_inputs)
#define NB 2
#define SEQ 2048
#define NH 16
#define DNOPE 128
#define DROT 64
#define DVDIM 128
#define DQK 192
#define BM 64
#define BN 64

typedef __bf16 bf16x8_t __attribute__((ext_vector_type(8)));
typedef float f32x4_t __attribute__((ext_vector_type(4)));

// log2(10000)/32 — inv_freq_i = 2^(-i * this); YaRN collapses (SCALING_FACTOR==1)
#define LOG2_BASE_OVER_HALFDIM 0.41524101186092028f
// 192^-0.5 * log2(e), folded into Q at bf16-convert time
#define KSL2 0.10412340175817158f
// 1/(2*pi) — radians -> revolutions for v_sin_f32/v_cos_f32
#define INV_2PI 0.15915494309189535f

// ws layout
#define KBF_ELEMS   ((size_t)NB * NH * SEQ * DQK)          // 12,582,912

// prep grid: uniform-branch block ranges (no intra-wave divergence)
#define KN_BLOCKS 4096   // NB*NH*SEQ*DNOPE /8/256  : nope copy
#define KR_BLOCKS 128    // NB*SEQ*DROT    /8/256  : rope (dedup over h, x16 stores)
#define VPREP_BLOCKS 1024 // V transpose

// ---------------------------------------------------------------------------
// Fused prep, branch-uniform per block:
//  [0, 4096)        : K-nope copy  f32 -> bf16 into Kbf[b][h][s][0..128)
//  [4096, 4224)     : rope(k_pe)   computed ONCE per (b,s) (H=1 source),
//                     broadcast-stored to all 16 heads at [128..192).
//                     Trig: v_sin/v_cos via revolutions + fract (HW transcendental,
//                     ~1e-4 rad angle err << bf16 quantization).
//  [4224, 5248)     : V transpose -> Vtb[b][h][dv][s] bf16
// ---------------------------------------------------------------------------
__global__ __launch_bounds__(256) void prep_kernel(
    const float* __restrict__ k_nope, const float* __restrict__ k_pe,
    const float* __restrict__ v, __bf16* __restrict__ Kbf,
    __bf16* __restrict__ Vtb) {
  __shared__ __bf16 T[64][130];
  const int bid = blockIdx.x;
  const int tid = threadIdx.x;
  if (bid < KN_BLOCKS) {
    // ---- nope copy: 8 elems/thread, d0 fastest (dest-contiguous)
    int gid = bid * 256 + tid;
    int d0 = (gid & 15) * 8;                    // within 128
    int rest = gid >> 4;                        // (b*2048+s)*16+h ... decode:
    int s = (rest >> 4) & (SEQ - 1);
    int h = rest & (NH - 1);
    int b = rest >> 15;
    const float* p = k_nope + ((size_t)((b * SEQ + s) * NH + h)) * DNOPE + d0;
    float4 a = *(const float4*)p;
    float4 c = *(const float4*)(p + 4);
    bf16x8_t o;
    o[0] = (__bf16)a.x; o[1] = (__bf16)a.y; o[2] = (__bf16)a.z; o[3] = (__bf16)a.w;
    o[4] = (__bf16)c.x; o[5] = (__bf16)c.y; o[6] = (__bf16)c.z; o[7] = (__bf16)c.w;
    *(bf16x8_t*)&Kbf[((size_t)(b * NH + h) * SEQ + s) * DQK + d0] = o;
  } else if (bid < KN_BLOCKS + KR_BLOCKS) {
    // ---- rope: one (b,s,dr0..dr0+7) group per thread; 16x h-broadcast store
    int gid = (bid - KN_BLOCKS) * 256 + tid;    // 0..32767
    int dr0 = (gid & 7) * 8;                    // {0,8,...,56}
    int rest = gid >> 3;
    int s = rest & (SEQ - 1);
    int b = rest >> 11;
    const float* p = k_pe + (size_t)(b * SEQ + s) * DROT;
    float4 x0 = *(const float4*)(p + dr0);
    float4 x1 = *(const float4*)(p + dr0 + 4);
    int dro = (dr0 < 32) ? dr0 + 32 : dr0 - 32;
    float4 y0 = *(const float4*)(p + dro);
    float4 y1 = *(const float4*)(p + dro + 4);
    float sgn = (dr0 < 32) ? -1.0f : 1.0f;
    float xs[8] = {x0.x, x0.y, x0.z, x0.w, x1.x, x1.y, x1.z, x1.w};
    float ys[8] = {y0.x, y0.y, y0.z, y0.w, y1.x, y1.y, y1.z, y1.w};
    // invf_j = 2^(-c*(i0+j)) = invf0 * 2^(-c*j); fold the j-part into literals
    float invf0 = exp2f(-LOG2_BASE_OVER_HALFDIM * (float)(dr0 & 31));
    const float kj[8] = {
      1.0f,
      0.7499083907567589f,   // 2^(-c*1)
      0.5624875938672282f,   // 2^(-c*2)
      0.4219181499736729f,   // 2^(-c*3)
      0.3163923045408737f,   // 2^(-c*4)
      0.2372497216250197f,   // 2^(-c*5)
      0.1779391804261401f,   // 2^(-c*6)
      0.1334543036472316f};  // 2^(-c*7)
    bf16x8_t o;
#pragma unroll
    for (int j = 0; j < 8; ++j) {
      float rev = (float)s * invf0 * (kj[j] * INV_2PI);
      rev = rev - floorf(rev);
      float sn = __builtin_amdgcn_sinf(rev);
      float cs = __builtin_amdgcn_cosf(rev);
      o[j] = (__bf16)(xs[j] * cs + sgn * ys[j] * sn);
    }
#pragma unroll
    for (int h = 0; h < NH; ++h)
      *(bf16x8_t*)&Kbf[((size_t)(b * NH + h) * SEQ + s) * DQK + DNOPE + dr0] = o;
  } else {
    int vb = bid - KN_BLOCKS - KR_BLOCKS;
    const int s0 = (vb & 31) * 64, h = (vb >> 5) & (NH - 1), b = vb >> 9;
#pragma unroll
    for (int r = 0; r < 8; ++r) {
      int task = tid + r * 256;                 // 0..2047
      int srow = task >> 5, c4 = (task & 31) * 4;
      const float* p = v + ((size_t)((b * SEQ + s0 + srow) * NH + h)) * DVDIM + c4;
      float4 a = *(const float4*)p;
      T[srow][c4 + 0] = (__bf16)a.x; T[srow][c4 + 1] = (__bf16)a.y;
      T[srow][c4 + 2] = (__bf16)a.z; T[srow][c4 + 3] = (__bf16)a.w;
    }
    __syncthreads();
#pragma unroll
    for (int r = 0; r < 4; ++r) {
      int task = tid + r * 256;                 // 0..1023
      int dv = task >> 3, c8 = (task & 7) * 8;
      bf16x8_t o;
#pragma unroll
      for (int u = 0; u < 8; ++u) o[u] = T[c8 + u][dv];
      *(bf16x8_t*)&Vtb[((size_t)(b * NH + h) * DVDIM + dv) * SEQ + s0 + c8] = o;
    }
  }
}

// ---------------------------------------------------------------------------
// Flash attention fwd — VERBATIM round-0 structure (proven 124.7 us control).
// Grid (16, NH, NB): WG bx handles q-tile pair {31-bx, bx} -> exactly 33
// k-iterations per WG (perfect balance, all 512 WGs co-resident 2/CU).
// Round-3 lesson: 1024-WG grid + 3-blocks/CU does NOT materialize (occupancy
// stays 19.9%) and adds a dispatch tail -> slower. Keep the paired scheme.
// Register-prefetch pipeline: tile it+1 is loaded into VGPRs while tile it
// is computed; LDS commit is 10 ds_write_b128 between the two barriers.
// LDS tiles are 16B blocks with XOR swizzle (all MFMA ds_read_b128 2-way/free).
// l is accumulated by MFMA against a static ones-column tile Vx (flash l
// recurrence == extra output column), killing the per-row sum reduction.
// ---------------------------------------------------------------------------
__global__ __launch_bounds__(256, 2) void mla_fwd_kernel(
    const float* __restrict__ q_nope, const float* __restrict__ q_pe,
    const __bf16* __restrict__ Kbf, const __bf16* __restrict__ Vtb,
    float* __restrict__ out_o, float* __restrict__ out_lse) {
  __shared__ __bf16 Kl[BN * DQK];       // 24576 B
  __shared__ __bf16 Vl[DVDIM * BN];     // 16384 B
  __shared__ __bf16 Pl[4 * 16 * BN];    //  8192 B
  __shared__ __bf16 Vx[16 * 72];        //  2304 B  (ones-column tile)

  const int bx = blockIdx.x, h = blockIdx.y, b = blockIdx.z;
  const int tid = threadIdx.x;
  const int w = tid >> 6, lane = tid & 63;
  const int col = lane & 15, quad = lane >> 4;
  const int swz = col & 7;
  const int e0 = quad ^ swz, e1 = (quad + 4) ^ swz;   // swizzled block slots

  // static ones-column tile: row 0 = ones over 64 keys, rows 1..15 = 0
  for (int i = tid; i < 16 * 72; i += 256)
    Vx[i] = (i < 64) ? (__bf16)1.0f : (__bf16)0.0f;

  const __bf16* Kslab = Kbf + (size_t)(b * NH + h) * SEQ * DQK;
  const __bf16* Vslab = Vtb + (size_t)(b * NH + h) * DVDIM * SEQ;

  // staging source offsets (swizzle folded into global source index)
  int kofs[6];
#pragma unroll
  for (int r = 0; r < 6; ++r) {
    int L = r * 256 + tid;                 // linear 16B block 0..1535
    int n = L / 24, jj = L - n * 24;
    int jsrc = (jj & ~7) | ((jj & 7) ^ (n & 7));
    kofs[r] = n * DQK + jsrc * 8;
  }
  int vofs[4];
#pragma unroll
  for (int r = 0; r < 4; ++r) {
    int L = r * 256 + tid;                 // 0..1023
    int dv = L >> 3, jj = L & 7;
    vofs[r] = dv * SEQ + (jj ^ (dv & 7)) * 8;
  }

  __syncthreads();                         // Vx visible
  const bf16x8_t vxf0 = *(const bf16x8_t*)&Vx[col * 72 + quad * 8];
  const bf16x8_t vxf1 = *(const bf16x8_t*)&Vx[col * 72 + 32 + quad * 8];

  for (int half = 0; half < 2; ++half) {
    const int qt = half ? bx : (31 - bx);
    const int qb = qt * BM;
    const int mrow = qb + w * 16 + col;

    // ---- Q fragments (A-layout: A[m=lane&15][k=quad*8+j]); scale folded in;
    // rope chunks 4,5 computed with inline sincosf (8 calls, once per half).
    const float* qn = q_nope + (size_t)((b * SEQ + mrow) * NH + h) * DNOPE;
    const float* qp = q_pe   + (size_t)((b * SEQ + mrow) * NH + h) * DROT;
    bf16x8_t qfrag[6];
#pragma unroll
    for (int c = 0; c < 4; ++c) {
      const float* p = qn + c * 32 + quad * 8;
      float4 a = *(const float4*)p;
      float4 bq = *(const float4*)(p + 4);
      bf16x8_t f;
      f[0]=(__bf16)(a.x*KSL2);  f[1]=(__bf16)(a.y*KSL2);
      f[2]=(__bf16)(a.z*KSL2);  f[3]=(__bf16)(a.w*KSL2);
      f[4]=(__bf16)(bq.x*KSL2); f[5]=(__bf16)(bq.y*KSL2);
      f[6]=(__bf16)(bq.z*KSL2); f[7]=(__bf16)(bq.w*KSL2);
      qfrag[c] = f;
    }
    {
      const float* plo = qp + quad * 8;
      const float* phi = qp + 32 + quad * 8;
      float4 lo0 = *(const float4*)plo;
      float4 lo1 = *(const float4*)(plo + 4);
      float4 hi0 = *(const float4*)phi;
      float4 hi1 = *(const float4*)(phi + 4);
      float xl[8] = {lo0.x,lo0.y,lo0.z,lo0.w,lo1.x,lo1.y,lo1.z,lo1.w};
      float xh[8] = {hi0.x,hi0.y,hi0.z,hi0.w,hi1.x,hi1.y,hi1.z,hi1.w};
      bf16x8_t f4v, f5v;
#pragma unroll
      for (int j = 0; j < 8; ++j) {
        int i = quad * 8 + j;
        float invf = exp2f(-LOG2_BASE_OVER_HALFDIM * (float)i);
        float ang = (float)mrow * invf;
        float sn, cs; sincosf(ang, &sn, &cs);
        f4v[j] = (__bf16)((xl[j] * cs - xh[j] * sn) * KSL2);
        f5v[j] = (__bf16)((xh[j] * cs + xl[j] * sn) * KSL2);
      }
      qfrag[4] = f4v; qfrag[5] = f5v;
    }

    f32x4_t oacc[8];
#pragma unroll
    for (int i = 0; i < 8; ++i) oacc[i] = (f32x4_t){0.f, 0.f, 0.f, 0.f};
    f32x4_t lacc = (f32x4_t){0.f, 0.f, 0.f, 0.f};
    float m_run[4] = {-INFINITY, -INFINITY, -INFINITY, -INFINITY};

    // ---- prologue: load tile 0 into registers
    bf16x8_t Kreg[6], Vreg[4];
#pragma unroll
    for (int r = 0; r < 6; ++r) Kreg[r] = *(const bf16x8_t*)(Kslab + kofs[r]);
#pragma unroll
    for (int r = 0; r < 4; ++r) Vreg[r] = *(const bf16x8_t*)(Vslab + vofs[r]);

    for (int it = 0; it <= qt; ++it) {
      __syncthreads();                     // prev readers done before overwrite
      // commit registers to LDS (10 x ds_write_b128, conflict-free)
#pragma unroll
      for (int r = 0; r < 6; ++r) *(bf16x8_t*)&Kl[(r * 256 + tid) * 8] = Kreg[r];
#pragma unroll
      for (int r = 0; r < 4; ++r) *(bf16x8_t*)&Vl[(r * 256 + tid) * 8] = Vreg[r];
      __syncthreads();                     // writes visible
      // prefetch tile it+1 (latency overlaps the whole compute phase)
      if (it < qt) {
        const __bf16* Ksrc = Kslab + (size_t)(it + 1) * BN * DQK;
        const __bf16* Vsrc = Vslab + (it + 1) * BN;
#pragma unroll
        for (int r = 0; r < 6; ++r) Kreg[r] = *(const bf16x8_t*)(Ksrc + kofs[r]);
#pragma unroll
        for (int r = 0; r < 4; ++r) Vreg[r] = *(const bf16x8_t*)(Vsrc + vofs[r]);
      }

      // ---- S = Q K^T : 4 n-tiles, 6 K-chunks (pre-scaled, log2 domain)
      f32x4_t sacc[4];
#pragma unroll
      for (int t = 0; t < 4; ++t) sacc[t] = (f32x4_t){0.f, 0.f, 0.f, 0.f};
#pragma unroll
      for (int t = 0; t < 4; ++t) {
        const __bf16* kr = &Kl[(t * 16 + col) * 24 * 8];
        sacc[t] = __builtin_amdgcn_mfma_f32_16x16x32_bf16(qfrag[0], *(const bf16x8_t*)&kr[e0 * 8], sacc[t], 0, 0, 0);
        sacc[t] = __builtin_amdgcn_mfma_f32_16x16x32_bf16(qfrag[1], *(const bf16x8_t*)&kr[e1 * 8], sacc[t], 0, 0, 0);
        sacc[t] = __builtin_amdgcn_mfma_f32_16x16x32_bf16(qfrag[2], *(const bf16x8_t*)&kr[64 + e0 * 8], sacc[t], 0, 0, 0);
        sacc[t] = __builtin_amdgcn_mfma_f32_16x16x32_bf16(qfrag[3], *(const bf16x8_t*)&kr[64 + e1 * 8], sacc[t], 0, 0, 0);
        sacc[t] = __builtin_amdgcn_mfma_f32_16x16x32_bf16(qfrag[4], *(const bf16x8_t*)&kr[128 + e0 * 8], sacc[t], 0, 0, 0);
        sacc[t] = __builtin_amdgcn_mfma_f32_16x16x32_bf16(qfrag[5], *(const bf16x8_t*)&kr[128 + e1 * 8], sacc[t], 0, 0, 0);
      }

      // ---- online softmax (log2 domain; only the max needs a reduction)
      const bool diag = (it == qt);
      float pv[4][4];
      float alpha[4];
#pragma unroll
      for (int r = 0; r < 4; ++r) {
        float mx = -INFINITY;
#pragma unroll
        for (int t = 0; t < 4; ++t) {
          float sv = sacc[t][r];
          if (diag) {
            int nn = (qt << 6) + t * 16 + col;
            int mm = qb + w * 16 + quad * 4 + r;
            if (nn > mm) sv = -INFINITY;
          }
          pv[t][r] = sv;
          mx = fmaxf(mx, sv);
        }
        mx = fmaxf(mx, __shfl_xor(mx, 1, 64));
        mx = fmaxf(mx, __shfl_xor(mx, 2, 64));
        mx = fmaxf(mx, __shfl_xor(mx, 4, 64));
        mx = fmaxf(mx, __shfl_xor(mx, 8, 64));
        float mnew = fmaxf(m_run[r], mx);
        alpha[r] = exp2f(m_run[r] - mnew);
        m_run[r] = mnew;
#pragma unroll
        for (int t = 0; t < 4; ++t) pv[t][r] = exp2f(pv[t][r] - mnew);
      }
#pragma unroll
      for (int d = 0; d < 8; ++d) {
        f32x4_t o = oacc[d];
        o[0] *= alpha[0]; o[1] *= alpha[1]; o[2] *= alpha[2]; o[3] *= alpha[3];
        oacc[d] = o;
      }
      lacc[0] *= alpha[0]; lacc[1] *= alpha[1];
      lacc[2] *= alpha[2]; lacc[3] *= alpha[3];

      // ---- P: C-layout regs -> swizzled per-wave LDS -> A-layout frags
      __bf16* Pw = &Pl[w * 16 * BN];
#pragma unroll
      for (int t = 0; t < 4; ++t)
#pragma unroll
        for (int r = 0; r < 4; ++r) {
          int row = quad * 4 + r;
          int j = t * 2 + (col >> 3);
          Pw[(row * 8 + (j ^ (row & 7))) * 8 + (col & 7)] = (__bf16)pv[t][r];
        }
      bf16x8_t pf0 = *(const bf16x8_t*)&Pw[(col * 8 + e0) * 8];
      bf16x8_t pf1 = *(const bf16x8_t*)&Pw[(col * 8 + e1) * 8];

      // ---- O += P V ; l += P * ones (extra static tile)
#pragma unroll
      for (int d = 0; d < 8; ++d) {
        const __bf16* vr = &Vl[(d * 16 + col) * 64];
        bf16x8_t vf0 = *(const bf16x8_t*)&vr[e0 * 8];
        bf16x8_t vf1 = *(const bf16x8_t*)&vr[e1 * 8];
        oacc[d] = __builtin_amdgcn_mfma_f32_16x16x32_bf16(pf0, vf0, oacc[d], 0, 0, 0);
        oacc[d] = __builtin_amdgcn_mfma_f32_16x16x32_bf16(pf1, vf1, oacc[d], 0, 0, 0);
      }
      lacc = __builtin_amdgcn_mfma_f32_16x16x32_bf16(pf0, vxf0, lacc, 0, 0, 0);
      lacc = __builtin_amdgcn_mfma_f32_16x16x32_bf16(pf1, vxf1, lacc, 0, 0, 0);
    }

    // ---- epilogue: broadcast l from col-0 lanes, normalize, store
    float lr[4];
#pragma unroll
    for (int r = 0; r < 4; ++r) lr[r] = __shfl(lacc[r], lane & 48, 64);
    float inv_l[4];
#pragma unroll
    for (int r = 0; r < 4; ++r) inv_l[r] = 1.0f / lr[r];
#pragma unroll
    for (int d = 0; d < 8; ++d) {
#pragma unroll
      for (int r = 0; r < 4; ++r) {
        int mm = qb + w * 16 + quad * 4 + r;
        out_o[(size_t)((b * SEQ + mm) * NH + h) * DVDIM + d * 16 + col] = oacc[d][r] * inv_l[r];
      }
    }
    if (col < 4) {
      int r = col;
      int mm = qb + w * 16 + quad * 4 + r;
      out_lse[(size_t)(b * SEQ + mm) * NH + h] = m_run[r] + log2f(lr[r]);
    }
  }
}

// ---------------------------------------------------------------------------
extern "C" void kernel_launch(void* const* d_in, const int* in_sizes, int n_in,
                              void* d_out, int out_size, void* d_ws, size_t ws_size,
                              hipStream_t stream) {
  const float* q_nope = (const float*)d_in[0];
  const float* q_pe   = (const float*)d_in[1];
  const float* k_nope = (const float*)d_in[2];
  const float* k_pe   = (const float*)d_in[3];
  const float* v      = (const float*)d_in[4];
  float* out_o   = (float*)d_out;
  float* out_lse = out_o + (size_t)NB * SEQ * NH * DVDIM;

  __bf16* Kbf = (__bf16*)d_ws;
  __bf16* Vtb = Kbf + KBF_ELEMS;   // total ws use ~40 MB

  prep_kernel<<<dim3(KN_BLOCKS + KR_BLOCKS + VPREP_BLOCKS), dim3(256), 0, stream>>>(
      k_nope, k_pe, v, Kbf, Vtb);
  mla_fwd_kernel<<<dim3(16, NH, NB), dim3(256), 0, stream>>>(
      q_nope, q_pe, Kbf, Vtb, out_o, out_lse);
}